// Round 10
// baseline (132.973 us; speedup 1.0000x reference)
//
#include <hip/hip_runtime.h>

// ---------------------------------------------------------------------------
// Convnet: 8 overlapping sections, conv [32x16] x 128 ch, threshold 15, pool
// (400,16), winner-take-all -> single channel index.
//
// R10: (a) pool stored as per-(c,fp) section bitmasks via atomicOr -> winner
//      reads 1920 ints with full MLP instead of 15360 with an 8-way gather
//      (the 1-block winner was ~17 us of the ~58 us non-conv residual).
//      (b) conv K-loop fully unrolled (40-reg headroom for cross-chunk
//      ds_read hoisting). R9 barrier-free structure otherwise unchanged.
// ---------------------------------------------------------------------------

using int4v  = __attribute__((ext_vector_type(4))) int;
using int8v  = __attribute__((ext_vector_type(8))) int;
using f32x16 = __attribute__((ext_vector_type(16))) float;

#define THRESH 15.0f
#define SCALE1 0x7F7F7F7F   // E8M0 127 = 2^0 in every byte

// ---------------- prep: W fp32 -> fp8 e4m3, B layout (per section, 64 KB):
//   addr = s*65536 + cc*8192 + ko*4096 + half*2048 + c*16 + byte
__global__ __launch_bounds__(256) void prep_kernel(const float* __restrict__ W,
                                                   unsigned char* __restrict__ Wp8,
                                                   int* __restrict__ pool2) {
  int t = blockIdx.x * 256 + threadIdx.x;   // 64 blocks -> 16384 threads
  if (t < 1920) pool2[t] = 0;
  int s = t >> 11, r = t & 2047, c = r >> 4, b = r & 15;   // b = k32 block
  const float* src = W + ((s * 128 + c) * 512 + b * 32);
  int4v lo, hi;
#pragma unroll
  for (int i = 0; i < 4; ++i) {
    float4 v = *(const float4*)(src + i * 4);
    int p = 0;
    p = __builtin_amdgcn_cvt_pk_fp8_f32(v.x, v.y, p, false);
    p = __builtin_amdgcn_cvt_pk_fp8_f32(v.z, v.w, p, true);
    lo[i] = p;
    float4 u = *(const float4*)(src + 16 + i * 4);
    int q = 0;
    q = __builtin_amdgcn_cvt_pk_fp8_f32(u.x, u.y, q, false);
    q = __builtin_amdgcn_cvt_pk_fp8_f32(u.z, u.w, q, true);
    hi[i] = q;
  }
  unsigned char* base = Wp8 + s * 65536 + (b >> 1) * 8192 + (b & 1) * 4096 + c * 16;
  *(int4v*)(base)        = lo;   // half 0: taps 0..15 of this k32 block
  *(int4v*)(base + 2048) = hi;   // half 1: taps 16..31
}

// ---------------- conv + threshold + pool-OR (bitmask per (c,fp))
// grid: 8 s * 13 t-tiles(32) * 30 fo-tiles(8) = 3120 blocks, 256 threads
// block: M = 256 (32 t x 8 fo), N = 128 ch, K = 512 (k = kt*16+kf)
// wave w: fo offsets {2w, 2w+1}; mfma_scale_f32_32x32x64_f8f6f4:
//   lane holds A[m=lane&31][k=(lane>>5)*32+j], B[k][n=lane&31], D col = lane&31.
__global__ __launch_bounds__(256, 2) void conv_pool_kernel(const float* __restrict__ X,
                                                           const unsigned char* __restrict__ Wp8,
                                                           int* __restrict__ pool2) {
  __shared__ __align__(16) unsigned char Ash[8 * 1008];   // 8064 B, 8 fo-shifted copies
  __shared__ __align__(16) unsigned char Bsh[65536];      // whole section's W, fp8
  __shared__ unsigned poolbits[32];

  const int tid = threadIdx.x;
  const int bid = blockIdx.x;
  const int s   = bid / 390;
  const int rem = bid % 390;
  const int tt  = rem / 30;
  const int ft  = rem % 30;
  const int t0  = (tt == 12) ? 368 : tt * 32;   // overlap recompute; OR idempotent
  const int fo0 = ft * 8, fp = ft >> 1;
  const int srow = s * 400 + t0;                // max 3168; +62 = 3230 in-bounds

  if (tid < 32) poolbits[tid] = 0;

  // ---- issue whole-W DMA: 4096 x 16 B, 16 per thread (drained by the barrier)
  {
    const unsigned char* wbase = Wp8 + s * 65536;
#pragma unroll
    for (int it = 0; it < 16; ++it) {
      int off = (it * 256 + tid) * 16;
      __builtin_amdgcn_global_load_lds(
          (const __attribute__((address_space(1))) void*)(wbase + off),
          (__attribute__((address_space(3))) void*)(&Bsh[off]), 16, 0, 0);
    }
  }

  // ---- stage A: 8 d x 63 rows x 16 fp8 (stride-16 writes, conflict-free)
  for (int i = tid; i < 504; i += 256) {
    int d = i / 63, r = i % 63;
    const float* xs = X + (srow + r) * 256 + fo0 + d;
    int4v pk;
#pragma unroll
    for (int h = 0; h < 4; ++h) {
      int q = 0;
      q = __builtin_amdgcn_cvt_pk_fp8_f32(xs[h * 4 + 0], xs[h * 4 + 1], q, false);
      q = __builtin_amdgcn_cvt_pk_fp8_f32(xs[h * 4 + 2], xs[h * 4 + 3], q, true);
      pk[h] = q;
    }
    *(int4v*)&Ash[d * 1008 + r * 16] = pk;
  }

  f32x16 acc[2][4];
#pragma unroll
  for (int a = 0; a < 2; ++a)
#pragma unroll
    for (int b = 0; b < 4; ++b)
#pragma unroll
      for (int e = 0; e < 16; ++e) acc[a][b][e] = 0.f;

  const int w = tid >> 6, l = tid & 63;
  const int m31 = l & 31, ko = l >> 5;

  // per-lane LDS base offsets (bytes)
  const int aoff0 = (2 * w) * 1008 + m31 * 16 + ko * 32;       // + ch*64 (+16 hi)
  const int aoff1 = (2 * w + 1) * 1008 + m31 * 16 + ko * 32;
  const int boff  = ko * 4096 + m31 * 16;                      // + ch*8192 + nt*512 (+2048 hi)

  __syncthreads();   // W DMA + A copies + poolbits all ready; only barrier

  // ---- barrier-free K loop: 8 chunks of 64 taps, pure ds_read + MFMA
#pragma unroll
  for (int ch = 0; ch < 8; ++ch) {
    // A frags: rows kt = ch*4 + ko*2 + {0,1} (+m31 conv shift), 2x16 B contiguous
    int4v a0lo = *(const int4v*)&Ash[aoff0 + ch * 64];
    int4v a0hi = *(const int4v*)&Ash[aoff0 + ch * 64 + 16];
    int4v a1lo = *(const int4v*)&Ash[aoff1 + ch * 64];
    int4v a1hi = *(const int4v*)&Ash[aoff1 + ch * 64 + 16];
    int8v A0 = {a0lo[0], a0lo[1], a0lo[2], a0lo[3], a0hi[0], a0hi[1], a0hi[2], a0hi[3]};
    int8v A1 = {a1lo[0], a1lo[1], a1lo[2], a1lo[3], a1hi[0], a1hi[1], a1hi[2], a1hi[3]};

    const unsigned char* bb = Bsh + ch * 8192 + boff;
#pragma unroll
    for (int nt = 0; nt < 4; ++nt) {
      int4v blo = *(const int4v*)(bb + nt * 512);          // half-plane 0
      int4v bhi = *(const int4v*)(bb + nt * 512 + 2048);   // half-plane 1
      int8v Bf = {blo[0], blo[1], blo[2], blo[3], bhi[0], bhi[1], bhi[2], bhi[3]};
      acc[0][nt] = __builtin_amdgcn_mfma_scale_f32_32x32x64_f8f6f4(
          A0, Bf, acc[0][nt], 0, 0, 0, SCALE1, 0, SCALE1);
      acc[1][nt] = __builtin_amdgcn_mfma_scale_f32_32x32x64_f8f6f4(
          A1, Bf, acc[1][nt], 0, 0, 0, SCALE1, 0, SCALE1);
    }
  }

  // ---- threshold + OR. Lane covers channels c = nt*32 + m31.
  unsigned sp = 0;
#pragma unroll
  for (int nt = 0; nt < 4; ++nt) {
    float m0 = -1e30f, m1 = -1e30f;
#pragma unroll
    for (int e = 0; e < 16; ++e) {
      m0 = fmaxf(m0, acc[0][nt][e]);
      m1 = fmaxf(m1, acc[1][nt][e]);
    }
    if (fmaxf(m0, m1) >= THRESH) sp |= (1u << nt);
  }
  sp |= __shfl_xor(sp, 32, 64);   // merge the two row-halves
  if (l < 32 && sp) atomicOr(&poolbits[m31], sp);
  __syncthreads();

  if (tid < 128) {
    unsigned bits = poolbits[tid & 31];
    if ((bits >> (tid >> 5)) & 1)
      atomicOr(&pool2[tid * 15 + fp], 1 << s);   // section bit for (c=tid, fp)
  }
}

// ---------------- winner (reference get_k_winners semantics) on 1920 bitmasks
__global__ __launch_bounds__(256) void winner_kernel(const int* __restrict__ pool2,
                                                     float* __restrict__ out) {
  __shared__ int sh_v;
  __shared__ int sh_best;
  int tid = threadIdx.x;
  if (tid == 0) { sh_v = 0; sh_best = 0; }
  __syncthreads();

  unsigned bArr[8];
  int localv = 0;
#pragma unroll
  for (int it = 0; it < 8; ++it) {
    int p = tid + it * 256;
    unsigned bits = (p < 1920) ? (unsigned)pool2[p] : 0u;
    bArr[it] = bits;
    if (bits) {
      int cnt = __popc(bits);
      int early = 8 - cnt; if (early > 7) early = 7;   // cnt>=1 -> early<=7
      localv |= (bits >> early) & 1;                   // pool[earliest]
    }
  }
  if (localv) atomicOr(&sh_v, 1);
  __syncthreads();

  const int v = sh_v * 8;   // trunc.max() * T
  int best = 0;
#pragma unroll
  for (int it = 0; it < 8; ++it) {
    int p = tid + it * 256;
    if (p < 1920) {
      unsigned bits = bArr[it];
      int cnt = __popc(bits);
      int early = 8 - cnt; if (early > 7) early = 7;
      int val = (bits >> early) & 1;
      int total = cnt * (val + v);
      int pack = (total << 12) | (4095 - p);   // max total, then smallest flat idx
      if (pack > best) best = pack;
    }
  }
  atomicMax(&sh_best, best);
  __syncthreads();

  if (tid == 0) {
    int total = sh_best >> 12;
    int p = 4095 - (sh_best & 4095);
    int feat = p / 15;
    out[0] = (total != 0) ? (float)feat : -1.0f;
  }
}

// ---------------------------------------------------------------------------
extern "C" void kernel_launch(void* const* d_in, const int* in_sizes, int n_in,
                              void* d_out, int out_size, void* d_ws, size_t ws_size,
                              hipStream_t stream) {
  (void)in_sizes; (void)n_in; (void)out_size; (void)ws_size;
  const float* X = (const float*)d_in[0];
  const float* W = (const float*)d_in[1];
  unsigned char* Wp8 = (unsigned char*)d_ws;               // 524,288 B
  int* pool2 = (int*)((char*)d_ws + (1 << 19));            // 7,680 B

  prep_kernel<<<64, 256, 0, stream>>>(W, Wp8, pool2);
  conv_pool_kernel<<<3120, 256, 0, stream>>>(X, Wp8, pool2);
  winner_kernel<<<1, 256, 0, stream>>>(pool2, (float*)d_out);
}